// Round 1
// baseline (81.482 us; speedup 1.0000x reference)
//
#include <hip/hip_runtime.h>
#include <hip/hip_bf16.h>
#include <cstdint>
#include <cstddef>

// Problem: B=8, T=2048, D=128 causal dual-mode attention.
// logits = scale * Qeff . K^T  with  Qeff[t][d] = -alpha*scale*q[t][d] + (1-alpha)*scale*q[t][(d+1)%D]
// (roll moved from K onto Q), then causal softmax, then @V.

typedef __attribute__((ext_vector_type(8))) short short8;
typedef __attribute__((ext_vector_type(4))) float f32x4;

#define T_DIM 2048
#define D_DIM 128
#define B_DIM 8

__device__ __forceinline__ unsigned short f2bf(float f) {
  unsigned u = __builtin_bit_cast(unsigned, f);
  u += 0x7FFFu + ((u >> 16) & 1u);          // RNE
  return (unsigned short)(u >> 16);
}

// ---------------- preprocess 1: K f32 -> bf16 (linear) ----------------
__global__ void cvt_k_kernel(const float* __restrict__ k, unsigned short* __restrict__ kbf) {
  int i = blockIdx.x * 256 + threadIdx.x;   // i < B*T*D/4 exactly
  float4 f = ((const float4*)k)[i];
  ushort4 o = { f2bf(f.x), f2bf(f.y), f2bf(f.z), f2bf(f.w) };
  ((ushort4*)kbf)[i] = o;
}

// ---------------- preprocess 2: V f32 [b][s][d] -> bf16 [b][d][s] ----------------
__global__ void tv_kernel(const float* __restrict__ v, unsigned short* __restrict__ vt) {
  __shared__ float tile[64][65];
  const int b = blockIdx.z, d0 = blockIdx.y * 64, s0 = blockIdx.x * 64;
  const int tid = threadIdx.x;
#pragma unroll
  for (int u = 0; u < 4; ++u) {
    int flat = u * 256 + tid; int r = flat >> 4, c4 = flat & 15;
    float4 f = *(const float4*)(v + ((size_t)b * T_DIM + s0 + r) * D_DIM + d0 + c4 * 4);
    tile[r][c4 * 4 + 0] = f.x; tile[r][c4 * 4 + 1] = f.y;
    tile[r][c4 * 4 + 2] = f.z; tile[r][c4 * 4 + 3] = f.w;
  }
  __syncthreads();
#pragma unroll
  for (int u = 0; u < 4; ++u) {
    int flat = u * 256 + tid; int dr = flat >> 4, sq = flat & 15;
    ushort4 o = { f2bf(tile[sq * 4 + 0][dr]), f2bf(tile[sq * 4 + 1][dr]),
                  f2bf(tile[sq * 4 + 2][dr]), f2bf(tile[sq * 4 + 3][dr]) };
    *(ushort4*)(vt + ((size_t)b * D_DIM + d0 + dr) * T_DIM + s0 + sq * 4) = o;
  }
}

// ---------------- main flash attention ----------------
// block = 128 threads (2 waves x 16 q-rows). KV tile = 64.
// LDS: K [64][128] bf16 swizzled (16KB) | Vt [128][64] bf16 swizzled (16KB) | P per-wave [16][72] bf16
#define KOFF 0
#define VOFF 16384
#define POFF 32768
#define PPITCH 144                 // bytes per P row (72 bf16), 16B aligned
#define SMEM_BYTES (32768 + 2 * 16 * PPITCH)

__global__ __launch_bounds__(128) void attn_kernel(
    const float* __restrict__ q, const unsigned short* __restrict__ kbf,
    const unsigned short* __restrict__ vt, const float* __restrict__ modep,
    float* __restrict__ out)
{
  __shared__ uint4 smem4[SMEM_BYTES / 16];
  char* smem = (char*)smem4;
  const int tid = threadIdx.x;
  const int w = tid >> 6;
  const int lane = tid & 63;
  const int t16 = lane & 15;       // q-row within wave tile / C-col index
  const int g = lane >> 4;         // 16-lane group id (0..3)
  const int x = blockIdx.x, b = blockIdx.y;
  // complementary-work mapping: co-resident (x,b)/(x,b+4) pairs sum to ~constant tiles
  const int chunk = (b < 4) ? x : (63 - x);
  const int qbase = chunk * 32 + w * 16;

  const float mode = modep[0];
  const float alpha = 1.0f / (1.0f + __expf(-mode));
  const float scale = 0.08838834764831845f;  // 1/sqrt(128)
  const float ca = -alpha * scale, cb = (1.0f - alpha) * scale;

  // ---- Qeff fragments (A-layout: row=t16, k = dd*32 + g*8 + i), scale folded ----
  short8 qf[4];
  const float* qrow = q + ((size_t)b * T_DIM + qbase + t16) * D_DIM;
#pragma unroll
  for (int dd = 0; dd < 4; ++dd) {
    int dstart = dd * 32 + g * 8;
    float e[9];
    float4 f0 = *(const float4*)(qrow + dstart);
    float4 f1 = *(const float4*)(qrow + dstart + 4);
    e[0] = f0.x; e[1] = f0.y; e[2] = f0.z; e[3] = f0.w;
    e[4] = f1.x; e[5] = f1.y; e[6] = f1.z; e[7] = f1.w;
    e[8] = qrow[(dstart + 8) & 127];
    short8 qv;
#pragma unroll
    for (int i = 0; i < 8; ++i)
      qv[i] = (short)f2bf(ca * e[i] + cb * e[i + 1]);
    qf[dd] = qv;
  }

  f32x4 acc[8];
#pragma unroll
  for (int dt = 0; dt < 8; ++dt) acc[dt] = (f32x4){0.f, 0.f, 0.f, 0.f};
  float mrun[4] = {-1e30f, -1e30f, -1e30f, -1e30f};
  float lrun[4] = {0.f, 0.f, 0.f, 0.f};

  const int nt = chunk / 2 + 1;     // KV tiles needed (causal)
  for (int kt = 0; kt < nt; ++kt) {
    const int kv0 = kt * 64;
    __syncthreads();
    // ---- stage K tile (bf16 copy, XOR-swizzled: byte ^= (s&7)<<4) ----
    const uint4* ksrc = (const uint4*)(kbf + ((size_t)b * T_DIM + kv0) * D_DIM);
#pragma unroll
    for (int u = 0; u < 8; ++u) {
      int c = u * 128 + tid;
      int s = c >> 4;
      uint4 val = ksrc[c];
      *(uint4*)(smem + ((c * 16) ^ ((s & 7) << 4))) = val;
    }
    // ---- stage Vt tile ([d][s], byte ^= (d&7)<<4) ----
#pragma unroll
    for (int u = 0; u < 8; ++u) {
      int c = u * 128 + tid;
      int d = c >> 3, sch = c & 7;
      uint4 val = *(const uint4*)(vt + ((size_t)b * D_DIM + d) * T_DIM + kv0 + sch * 8);
      *(uint4*)(smem + VOFF + ((c * 16) ^ ((d & 7) << 4))) = val;
    }
    __syncthreads();

    // ---- S = Qeff . K^T (C-layout: row m = 4g+r, col n = t16 -> s = jt*16+t16) ----
    f32x4 sj[4];
#pragma unroll
    for (int jt = 0; jt < 4; ++jt) {
      f32x4 sc = (f32x4){0.f, 0.f, 0.f, 0.f};
      int s = jt * 16 + t16;
      int rowbyte = s * 256, swz = (s & 7) << 4;
#pragma unroll
      for (int dd = 0; dd < 4; ++dd) {
        short8 kf = *(const short8*)(smem + ((rowbyte + dd * 64 + g * 16) ^ swz));
        sc = __builtin_amdgcn_mfma_f32_16x16x32_bf16(qf[dd], kf, sc, 0, 0, 0);
      }
      sj[jt] = sc;
    }

    // ---- causal mask + online softmax ----
    float tm[4] = {-1e30f, -1e30f, -1e30f, -1e30f};
#pragma unroll
    for (int jt = 0; jt < 4; ++jt) {
      int sg = kv0 + jt * 16 + t16;
#pragma unroll
      for (int r = 0; r < 4; ++r) {
        int tg = qbase + 4 * g + r;
        float sv = (sg <= tg) ? sj[jt][r] : -1e30f;
        sj[jt][r] = sv;
        tm[r] = fmaxf(tm[r], sv);
      }
    }
#pragma unroll
    for (int r = 0; r < 4; ++r) {
      tm[r] = fmaxf(tm[r], __shfl_xor(tm[r], 1));
      tm[r] = fmaxf(tm[r], __shfl_xor(tm[r], 2));
      tm[r] = fmaxf(tm[r], __shfl_xor(tm[r], 4));
      tm[r] = fmaxf(tm[r], __shfl_xor(tm[r], 8));
    }
    float corr[4], rs[4];
#pragma unroll
    for (int r = 0; r < 4; ++r) {
      float mnew = fmaxf(mrun[r], tm[r]);
      corr[r] = __expf(mrun[r] - mnew);
      mrun[r] = mnew;
      rs[r] = 0.f;
    }
#pragma unroll
    for (int jt = 0; jt < 4; ++jt)
#pragma unroll
      for (int r = 0; r < 4; ++r) {
        float p = __expf(sj[jt][r] - mrun[r]);
        sj[jt][r] = p;
        rs[r] += p;
      }
#pragma unroll
    for (int r = 0; r < 4; ++r) {
      rs[r] += __shfl_xor(rs[r], 1);
      rs[r] += __shfl_xor(rs[r], 2);
      rs[r] += __shfl_xor(rs[r], 4);
      rs[r] += __shfl_xor(rs[r], 8);
      lrun[r] = lrun[r] * corr[r] + rs[r];
    }
#pragma unroll
    for (int dt = 0; dt < 8; ++dt)
#pragma unroll
      for (int r = 0; r < 4; ++r) acc[dt][r] *= corr[r];

    // ---- P -> LDS (C-layout -> row-major [t][s]) ----
    char* pbase = smem + POFF + w * (16 * PPITCH);
#pragma unroll
    for (int jt = 0; jt < 4; ++jt)
#pragma unroll
      for (int r = 0; r < 4; ++r)
        *(unsigned short*)(pbase + (4 * g + r) * PPITCH + (jt * 16 + t16) * 2) = f2bf(sj[jt][r]);

    // ---- O += P . V  (A = P rows t16, B = Vt rows d) ----
#pragma unroll
    for (int k0 = 0; k0 < 2; ++k0) {
      short8 pf = *(const short8*)(pbase + t16 * PPITCH + k0 * 64 + g * 16);
#pragma unroll
      for (int dt = 0; dt < 8; ++dt) {
        int d = dt * 16 + t16;
        short8 vf = *(const short8*)(smem + VOFF + ((d * 128 + k0 * 64 + g * 16) ^ ((d & 7) << 4)));
        acc[dt] = __builtin_amdgcn_mfma_f32_16x16x32_bf16(pf, vf, acc[dt], 0, 0, 0);
      }
    }
  }

  // ---- epilogue: normalize + store f32 ----
#pragma unroll
  for (int r = 0; r < 4; ++r) {
    float inv = 1.0f / lrun[r];
#pragma unroll
    for (int dt = 0; dt < 8; ++dt)
      out[((size_t)b * T_DIM + qbase + 4 * g + r) * D_DIM + dt * 16 + t16] = acc[dt][r] * inv;
  }
}

extern "C" void kernel_launch(void* const* d_in, const int* in_sizes, int n_in,
                              void* d_out, int out_size, void* d_ws, size_t ws_size,
                              hipStream_t stream) {
  const float* q = (const float*)d_in[0];
  const float* k = (const float*)d_in[1];
  const float* v = (const float*)d_in[2];
  // d_in[3] = mask (causal tril, hardcoded)
  const float* mode = (const float*)d_in[4];
  float* out = (float*)d_out;

  unsigned short* kbf = (unsigned short*)d_ws;                                   // 4 MB
  unsigned short* vt  = (unsigned short*)((char*)d_ws + (size_t)B_DIM * T_DIM * D_DIM * 2); // 4 MB

  // K -> bf16
  cvt_k_kernel<<<(B_DIM * T_DIM * D_DIM / 4) / 256, 256, 0, stream>>>(k, kbf);
  // V -> bf16 transposed [b][d][s]
  tv_kernel<<<dim3(T_DIM / 64, D_DIM / 64, B_DIM), 256, 0, stream>>>(v, vt);
  // flash attention
  attn_kernel<<<dim3(64, B_DIM), 128, 0, stream>>>(q, kbf, vt, mode, out);
}